// Round 3
// baseline (1024.939 us; speedup 1.0000x reference)
//
#include <hip/hip_runtime.h>
#include <hip/hip_bf16.h>
#include <cstdint>
#include <cstddef>

// ---------------------------------------------------------------------------
// RetentiveSelfAttention on MI355X (gfx950)
// B=4, N=48*48=2304, D=768, H=12, d_head=64, scaling=64^-0.5=0.125
// Pipeline: pack(bf16) -> fused QKV NT-GEMM (MFMA) -> flash attention
//           (softmax then decay-mask) -> output NT-GEMM (fp32 out)
// R8: attn was latency-serialized: (256,3) => 170-reg cap => allocator sank
//     every early-issued load to its use (~20 sequential HBM RTTs/body,
//     17.7k cyc/body measured; MfmaUtil 4.4%, VALU 9%, HBM 6%).
//     Fix: (256,2) => 256-reg cap so the load batch stays hoisted, and
//     macro-expanded double-buffer bodies (no lambda refs) so all arrays
//     SROA into registers. Same math, same schedule as written.
// ---------------------------------------------------------------------------

typedef __attribute__((ext_vector_type(8))) short short8;   // 8 bf16 = 4 VGPRs
typedef __attribute__((ext_vector_type(4))) float floatx4;  // MFMA acc

#define MFMA_BF16 __builtin_amdgcn_mfma_f32_16x16x32_bf16

constexpr int BB   = 4;     // batch
constexpr int NH   = 12;    // heads
constexpr int SEQ  = 2304;  // N
constexpr int DIM  = 768;   // embed
constexpr int MROW = BB * SEQ;   // 9216
constexpr float SCALE = 0.125f;  // 64^-0.5

static __device__ __forceinline__ unsigned short f2b(float f) {
  union { float f; unsigned u; } v; v.f = f;
  unsigned r = (v.u + 0x7fffu + ((v.u >> 16) & 1u)) >> 16;  // RNE
  return (unsigned short)r;
}

// 2x f32 -> packed bf16 pair (RNE), single instruction on gfx950 (T12 recipe)
static __device__ __forceinline__ unsigned cvtpk_bf16(float a, float b) {
  unsigned r;
  asm("v_cvt_pk_bf16_f32 %0, %1, %2" : "=v"(r) : "v"(a), "v"(b));
  return r;
}

// async global->LDS, 16B per lane; LDS dest is wave-uniform base + lane*16
typedef unsigned int __attribute__((address_space(1))) as1_u32;
typedef unsigned int __attribute__((address_space(3))) as3_u32;
static __device__ __forceinline__ void gload16(const void* g, void* l) {
  __builtin_amdgcn_global_load_lds((as1_u32*)g, (as3_u32*)l, 16, 0, 0);
}

// ---------------------------------------------------------------------------
// Pack: x -> bf16; Wq|Wk*s|Wv -> bf16 fused [2304x768]; Wo -> bf16;
//       bq|bk*s|bv -> fp32 fused [2304]
// Vectorized: float4 loads + cvt_pk pairs + uint2 stores (all region
// boundaries are multiples of 4, so a chunk never straddles regions).
// ---------------------------------------------------------------------------
constexpr int NX = MROW * DIM;      // 7,077,888
constexpr int NW = DIM * DIM;       // 589,824
constexpr int NV4 = (NX + 4 * NW) / 4;   // float4 chunks over all bf16 outputs

__global__ void pack_kernel(const float* __restrict__ x,
                            const float* __restrict__ Wq, const float* __restrict__ bq,
                            const float* __restrict__ Wk, const float* __restrict__ bk,
                            const float* __restrict__ Wv, const float* __restrict__ bv,
                            const float* __restrict__ Wo,
                            unsigned short* __restrict__ xb,
                            unsigned short* __restrict__ Wqkv,
                            unsigned short* __restrict__ Wob,
                            float* __restrict__ biasqkv) {
  for (int v = blockIdx.x * blockDim.x + threadIdx.x; v < NV4 + 3 * DIM;
       v += gridDim.x * blockDim.x) {
    if (v < NV4) {
      const int e = v * 4;
      const float* src;
      unsigned short* dst;
      float sc = 1.0f;
      if (e < NX)                { src = x  + e;                dst = xb   + e; }
      else if (e < NX + NW)      { src = Wq + (e - NX);         dst = Wqkv + (e - NX); }
      else if (e < NX + 2 * NW)  { src = Wk + (e - NX - NW);    dst = Wqkv + (e - NX); sc = SCALE; }
      else if (e < NX + 3 * NW)  { src = Wv + (e - NX - 2*NW);  dst = Wqkv + (e - NX); }
      else                       { src = Wo + (e - NX - 3*NW);  dst = Wob  + (e - NX - 3*NW); }
      const float4 f = *(const float4*)src;
      uint2 o;
      o.x = cvtpk_bf16(f.x * sc, f.y * sc);
      o.y = cvtpk_bf16(f.z * sc, f.w * sc);
      *(uint2*)dst = o;
    } else {
      const int j = v - NV4;
      biasqkv[j] = (j < DIM) ? bq[j]
                 : (j < 2 * DIM) ? bk[j - DIM] * SCALE
                 : bv[j - 2 * DIM];
    }
  }
}

// ---------------------------------------------------------------------------
// NT GEMM: C[M,Nc] = A[M,K](bf16) @ B[Nc,K](bf16)^T + bias
// MODE 0: scatter to Q/K (per-head [b,h,row,64]) and V^T ([b,h,64,row]) bf16
// MODE 1: fp32 dense output [M,Nc]
// 128x128 block tile, BK=64, 4 waves (2x2), 16x16x32 MFMA, 4x4 tiles/wave.
// Staging: global_load_lds dwordx4 into LINEAR [128][64] LDS (m97 pattern).
//   Wave w, call c stage segment seg=w*4+c: LDS bytes [seg*1024, seg*1024+1024).
//   HW writes lane l at base + l*16; lane l's global src = row seg*8 + l/8,
//   col-bytes (l&7)*16  =>  linear row-major [128 rows][128 B]. Verified:
//   seg*1024 + (l/8)*128 + (l&7)*16 == seg*1024 + l*16.
// ---------------------------------------------------------------------------
template <int MODE>
__global__ __launch_bounds__(256)
void gemm_nt(const unsigned short* __restrict__ A,
             const unsigned short* __restrict__ Bm,
             const float* __restrict__ bias,
             int M, int Nc, int K,
             unsigned short* __restrict__ Qb,
             unsigned short* __restrict__ Kb,
             unsigned short* __restrict__ Vt,
             float* __restrict__ Out) {
  __shared__ __align__(16) unsigned short As[128][64];  // linear, no pad
  __shared__ __align__(16) unsigned short Bs[128][64];

  const int t    = threadIdx.x;
  const int m0   = blockIdx.x * 128;
  const int n0   = blockIdx.y * 128;
  const int w    = t >> 6;
  const int lane = t & 63, quad = lane >> 4, ln = lane & 15;
  const int wm = (w >> 1) * 64, wn = (w & 1) * 64;

  const int srow = lane >> 3;       // 0..7 within an 8-row segment
  const int scol = (lane & 7) * 8;  // element col: 0,8,...,56

  floatx4 acc[4][4] = {};

  for (int k0 = 0; k0 < K; k0 += 64) {
    __syncthreads();  // previous iter's fragment reads done before overwrite
#pragma unroll
    for (int c = 0; c < 4; ++c) {
      const int seg = w * 4 + c;          // 0..15
      const int r   = seg * 8 + srow;     // tile row this lane stages
      gload16(&A [(size_t)(m0 + r) * K + k0 + scol], &As[0][0] + seg * 512);
      gload16(&Bm[(size_t)(n0 + r) * K + k0 + scol], &Bs[0][0] + seg * 512);
    }
    __syncthreads();  // compiler emits s_waitcnt vmcnt(0) before s_barrier

#pragma unroll
    for (int s = 0; s < 2; ++s) {
      short8 af[4], bf[4];
#pragma unroll
      for (int i = 0; i < 4; ++i)
        af[i] = *(const short8*)&As[wm + i * 16 + ln][s * 32 + quad * 8];
#pragma unroll
      for (int j = 0; j < 4; ++j)
        bf[j] = *(const short8*)&Bs[wn + j * 16 + ln][s * 32 + quad * 8];
#pragma unroll
      for (int i = 0; i < 4; ++i)
#pragma unroll
        for (int j = 0; j < 4; ++j)
          acc[i][j] = MFMA_BF16(af[i], bf[j], acc[i][j], 0, 0, 0);
    }
  }

  // epilogue; C layout: col = ln, row = quad*4 + r  [measured m89/m91]
#pragma unroll
  for (int i = 0; i < 4; ++i) {
#pragma unroll
    for (int j = 0; j < 4; ++j) {
      const int n = n0 + wn + j * 16 + ln;
      const float bn = bias[n];
#pragma unroll
      for (int r = 0; r < 4; ++r) {
        const int m = m0 + wm + i * 16 + quad * 4 + r;
        const float val = acc[i][j][r] + bn;
        if (MODE == 0) {
          const int b = m / SEQ, row = m - b * SEQ;
          const int which = n / DIM, rem = n - which * DIM;
          const int h = rem >> 6, d = rem & 63;
          const size_t bh = (size_t)(b * NH + h);
          if (which == 0)      Qb[(bh * SEQ + row) * 64 + d] = f2b(val);
          else if (which == 1) Kb[(bh * SEQ + row) * 64 + d] = f2b(val);
          else                 Vt[(bh * 64 + d) * SEQ + row] = f2b(val);
        } else {
          Out[(size_t)m * Nc + n] = val;
        }
      }
    }
  }
}

// ---------------------------------------------------------------------------
// Flash attention, max-free softmax, post-softmax decay mask.
// grid = (144 q-tiles of 16 rows, 12 heads); block = 256 = 4 waves.
// Wave w = batch w; all 4 waves cover the SAME q-rows & decay rows (L1
// sharing -> decay HBM demand exactly 255 MB). No barriers (per-wave LDS).
// Per key-tile (64 keys), software-pipelined:
//   issue V + decay loads early | S = Q K^T (MFMA, K from regs) |
//   prefetch K(jt+1) | exp(S)->LDS C-layout | read A-layout (decay rows
//   contiguous) | den+=, pack bf16 via v_cvt_pk_bf16_f32 | O += P V.
// R8: launch_bounds(256,2) — 256-VGPR cap so the per-body load batch stays
//     hoisted (at 170 the allocator sank loads to uses: ~20 serial RTTs).
//     Bodies macro-expanded with direct kA/kB names (no lambda references).
// Epilogue: den reduced across quads (2 shuffles), O/den -> bf16.
// ---------------------------------------------------------------------------
__global__ __launch_bounds__(256, 2)
void attn_kernel(const unsigned short* __restrict__ Qb,
                 const unsigned short* __restrict__ Kb,
                 const unsigned short* __restrict__ Vt,
                 const float* __restrict__ decay,
                 unsigned short* __restrict__ attn_b) {
  __shared__ __align__(16) float P_lds[4][16][68];  // per-wave 16x64 f32, +4 pad

  const int t = threadIdx.x;
  const int w = t >> 6;                 // batch
  const int lane = t & 63, quad = lane >> 4, ln = lane & 15;
  const int qt = blockIdx.x;
  const int h  = blockIdx.y;
  const int q0 = qt * 16;               // q-rows shared by all 4 waves

  const size_t bh = (size_t)(w * NH + h);
  const unsigned short* Qp = Qb + bh * SEQ * 64;
  const unsigned short* Kp = Kb + bh * SEQ * 64;
  const unsigned short* Vp = Vt + bh * 64 * SEQ;
  // A-side decay row for this lane (row = q0 + ln) — identical across waves
  const float* drow = decay + (size_t)h * SEQ * SEQ + (size_t)(q0 + ln) * SEQ;

  // Q fragments: A[m=ln][k=quad*8+j]
  short8 qf[2];
#pragma unroll
  for (int s = 0; s < 2; ++s)
    qf[s] = *(const short8*)&Qp[(size_t)(q0 + ln) * 64 + s * 32 + quad * 8];

  floatx4 O[4] = {};
  float den = 0.f;   // A-side partial: row = ln, this quad's key chunk

  short8 kA[2][4], kB[2][4];  // double-buffered K fragments
#pragma unroll
  for (int s = 0; s < 2; ++s)
#pragma unroll
    for (int tt = 0; tt < 4; ++tt)
      kA[s][tt] = *(const short8*)&Kp[(size_t)(tt * 16 + ln) * 64 + s * 32 + quad * 8];

  // One key-tile body. KC = current K fragments, KN = buffer for prefetch.
  // Textual expansion with direct array names => guaranteed SROA.
#define ATTN_BODY(KC, KN, JT)                                                 \
  {                                                                           \
    const int j0 = (JT) * 64;                                                 \
    const int jn = ((JT) + 1 < 36) ? ((JT) + 1) * 64 : 0;                     \
    float4 d0[2], d1[2];                                                      \
    short8 vf[2][4];                                                          \
    _Pragma("unroll")                                                         \
    for (int s = 0; s < 2; ++s) {                                             \
      const int kc_ = s * 32 + quad * 8;                                      \
      d0[s] = *(const float4*)&drow[j0 + kc_];                                \
      d1[s] = *(const float4*)&drow[j0 + kc_ + 4];                            \
      _Pragma("unroll")                                                       \
      for (int dt = 0; dt < 4; ++dt)                                          \
        vf[s][dt] = *(const short8*)&Vp[(size_t)(dt * 16 + ln) * SEQ + j0 + kc_]; \
    }                                                                         \
    floatx4 S[4] = {};                                                        \
    _Pragma("unroll")                                                         \
    for (int s = 0; s < 2; ++s)                                               \
      _Pragma("unroll")                                                       \
      for (int tt = 0; tt < 4; ++tt)                                          \
        S[tt] = MFMA_BF16(qf[s], KC[s][tt], S[tt], 0, 0, 0);                  \
    _Pragma("unroll")                                                         \
    for (int s = 0; s < 2; ++s)                                               \
      _Pragma("unroll")                                                       \
      for (int tt = 0; tt < 4; ++tt)                                          \
        KN[s][tt] = *(const short8*)&Kp[(size_t)(jn + tt * 16 + ln) * 64 + s * 32 + quad * 8]; \
    _Pragma("unroll")                                                         \
    for (int tt = 0; tt < 4; ++tt)                                            \
      _Pragma("unroll")                                                       \
      for (int r = 0; r < 4; ++r)                                             \
        P_lds[w][quad * 4 + r][tt * 16 + ln] = __expf(S[tt][r]);              \
    _Pragma("unroll")                                                         \
    for (int s = 0; s < 2; ++s) {                                             \
      const int kc_ = s * 32 + quad * 8;                                      \
      const float4 p0 = *(const float4*)&P_lds[w][ln][kc_];                   \
      const float4 p1 = *(const float4*)&P_lds[w][ln][kc_ + 4];               \
      den += (p0.x + p0.y + p0.z + p0.w) + (p1.x + p1.y + p1.z + p1.w);       \
      union { short8 s8; unsigned u[4]; } pu;                                 \
      pu.u[0] = cvtpk_bf16(p0.x * d0[s].x, p0.y * d0[s].y);                   \
      pu.u[1] = cvtpk_bf16(p0.z * d0[s].z, p0.w * d0[s].w);                   \
      pu.u[2] = cvtpk_bf16(p1.x * d1[s].x, p1.y * d1[s].y);                   \
      pu.u[3] = cvtpk_bf16(p1.z * d1[s].z, p1.w * d1[s].w);                   \
      _Pragma("unroll")                                                       \
      for (int dt = 0; dt < 4; ++dt)                                          \
        O[dt] = MFMA_BF16(pu.s8, vf[s][dt], O[dt], 0, 0, 0);                  \
    }                                                                         \
  }

  for (int jt2 = 0; jt2 < 18; ++jt2) {
    ATTN_BODY(kA, kB, 2 * jt2)
    ATTN_BODY(kB, kA, 2 * jt2 + 1)
  }
#undef ATTN_BODY

  // den: sum the 4 quad partials for each row ln (lanes ln,16+ln,32+ln,48+ln)
  den += __shfl_xor(den, 16);
  den += __shfl_xor(den, 32);
  // O is C-layout (row = quad*4+r); den for row m lives in lanes with ln==m
  float dinv[4];
#pragma unroll
  for (int r = 0; r < 4; ++r)
    dinv[r] = 1.0f / __shfl(den, quad * 4 + r);

#pragma unroll
  for (int dt = 0; dt < 4; ++dt)
#pragma unroll
    for (int r = 0; r < 4; ++r)
      attn_b[((size_t)(w * SEQ + q0 + quad * 4 + r)) * DIM + h * 64 + dt * 16 + ln]
          = f2b(O[dt][r] * dinv[r]);
}

// ---------------------------------------------------------------------------
extern "C" void kernel_launch(void* const* d_in, const int* in_sizes, int n_in,
                              void* d_out, int out_size, void* d_ws, size_t ws_size,
                              hipStream_t stream) {
  const float* x     = (const float*)d_in[0];
  const float* decay = (const float*)d_in[1];
  const float* Wq    = (const float*)d_in[2];
  const float* bq    = (const float*)d_in[3];
  const float* Wk    = (const float*)d_in[4];
  const float* bk    = (const float*)d_in[5];
  const float* Wv    = (const float*)d_in[6];
  const float* bv    = (const float*)d_in[7];
  const float* Wo    = (const float*)d_in[8];
  const float* bo    = (const float*)d_in[9];
  float* out = (float*)d_out;

  char* ws = (char*)d_ws;
  size_t off = 0;
  auto alloc = [&](size_t bytes) {
    void* p = ws + off;
    off += (bytes + 255) & ~(size_t)255;
    return p;
  };
  unsigned short* xb      = (unsigned short*)alloc((size_t)MROW * DIM * 2);  // 14.2 MB
  unsigned short* Wqkv    = (unsigned short*)alloc((size_t)3 * NW * 2);      //  3.5 MB
  unsigned short* Wob     = (unsigned short*)alloc((size_t)NW * 2);          //  1.2 MB
  float*          biasqkv = (float*)alloc((size_t)3 * DIM * 4);
  unsigned short* Qb      = (unsigned short*)alloc((size_t)MROW * DIM * 2);  // 14.2 MB
  unsigned short* Kb      = (unsigned short*)alloc((size_t)MROW * DIM * 2);  // 14.2 MB
  unsigned short* Vt      = (unsigned short*)alloc((size_t)MROW * DIM * 2);  // 14.2 MB
  unsigned short* attn_b  = xb;  // xb is dead after gemm<0>; alias (~61 MB total)
  (void)ws_size; (void)in_sizes; (void)n_in; (void)out_size;

  pack_kernel<<<4096, 256, 0, stream>>>(x, Wq, bq, Wk, bk, Wv, bv, Wo,
                                        xb, Wqkv, Wob, biasqkv);

  gemm_nt<0><<<dim3(MROW / 128, 2304 / 128), 256, 0, stream>>>(
      xb, Wqkv, biasqkv, MROW, 3 * DIM, DIM, Qb, Kb, Vt, nullptr);

  attn_kernel<<<dim3(SEQ / 16, NH), 256, 0, stream>>>(Qb, Kb, Vt, decay, attn_b);

  gemm_nt<1><<<dim3(MROW / 128, DIM / 128), 256, 0, stream>>>(
      attn_b, Wob, bo, MROW, DIM, DIM, nullptr, nullptr, nullptr, out);
}

// Round 6
// 757.372 us; speedup vs baseline: 1.3533x; 1.3533x over previous
//
#include <hip/hip_runtime.h>
#include <hip/hip_bf16.h>
#include <cstdint>
#include <cstddef>

// ---------------------------------------------------------------------------
// RetentiveSelfAttention on MI355X (gfx950)
// B=4, N=48*48=2304, D=768, H=12, d_head=64, scaling=64^-0.5=0.125
// Pipeline: pack(bf16) -> fused QKV NT-GEMM (MFMA) -> flash attention
//           (softmax then decay-mask) -> output NT-GEMM (fp32 out)
// R9-R11: attn staged via global_load_lds DMA (no landing registers; R8
//     showed the allocator pins 56 arch VGPRs and serializes every
//     register-landing load on a waitcnt, ~20 HBM RTTs/body).
// R11 FIX: R9 raced — STAGE(jt+1) was issued while vf ds_reads were only
//     ISSUED, not complete; VMEM-return LDS writes are unordered vs pending
//     DS reads, so hot DMA returns overwrote Vs before the reads executed.
//     Now the m97 two-barrier body: barrier A (tile jt DMA resident) ->
//     ds_read K/V frags -> barrier B (lgkm drained => reads COMPLETE on all
//     waves) -> STAGE(jt+1) -> compute. Swizzle pairs verified by concrete
//     lane examples (K/V/decay). KVBLK=32, LDS 45KB/block -> 3 blocks/CU.
// ---------------------------------------------------------------------------

typedef __attribute__((ext_vector_type(8))) short short8;   // 8 bf16 = 4 VGPRs
typedef __attribute__((ext_vector_type(4))) float floatx4;  // MFMA acc

#define MFMA_BF16 __builtin_amdgcn_mfma_f32_16x16x32_bf16

constexpr int BB   = 4;     // batch
constexpr int NH   = 12;    // heads
constexpr int SEQ  = 2304;  // N
constexpr int DIM  = 768;   // embed
constexpr int MROW = BB * SEQ;   // 9216
constexpr float SCALE = 0.125f;  // 64^-0.5

static __device__ __forceinline__ unsigned short f2b(float f) {
  union { float f; unsigned u; } v; v.f = f;
  unsigned r = (v.u + 0x7fffu + ((v.u >> 16) & 1u)) >> 16;  // RNE
  return (unsigned short)r;
}

// 2x f32 -> packed bf16 pair (RNE), single instruction on gfx950 (T12 recipe)
static __device__ __forceinline__ unsigned cvtpk_bf16(float a, float b) {
  unsigned r;
  asm("v_cvt_pk_bf16_f32 %0, %1, %2" : "=v"(r) : "v"(a), "v"(b));
  return r;
}

// async global->LDS, 16B per lane; LDS dest is wave-uniform base + lane*16
typedef unsigned int __attribute__((address_space(1))) as1_u32;
typedef unsigned int __attribute__((address_space(3))) as3_u32;
static __device__ __forceinline__ void gload16(const void* g, void* l) {
  __builtin_amdgcn_global_load_lds((const as1_u32*)g, (as3_u32*)l, 16, 0, 0);
}

// ---------------------------------------------------------------------------
// Pack: x -> bf16; Wq|Wk*s|Wv -> bf16 fused [2304x768]; Wo -> bf16;
//       bq|bk*s|bv -> fp32 fused [2304]
// ---------------------------------------------------------------------------
constexpr int NX = MROW * DIM;      // 7,077,888
constexpr int NW = DIM * DIM;       // 589,824
constexpr int NV4 = (NX + 4 * NW) / 4;   // float4 chunks over all bf16 outputs

__global__ void pack_kernel(const float* __restrict__ x,
                            const float* __restrict__ Wq, const float* __restrict__ bq,
                            const float* __restrict__ Wk, const float* __restrict__ bk,
                            const float* __restrict__ Wv, const float* __restrict__ bv,
                            const float* __restrict__ Wo,
                            unsigned short* __restrict__ xb,
                            unsigned short* __restrict__ Wqkv,
                            unsigned short* __restrict__ Wob,
                            float* __restrict__ biasqkv) {
  for (int v = blockIdx.x * blockDim.x + threadIdx.x; v < NV4 + 3 * DIM;
       v += gridDim.x * blockDim.x) {
    if (v < NV4) {
      const int e = v * 4;
      const float* src;
      unsigned short* dst;
      float sc = 1.0f;
      if (e < NX)                { src = x  + e;                dst = xb   + e; }
      else if (e < NX + NW)      { src = Wq + (e - NX);         dst = Wqkv + (e - NX); }
      else if (e < NX + 2 * NW)  { src = Wk + (e - NX - NW);    dst = Wqkv + (e - NX); sc = SCALE; }
      else if (e < NX + 3 * NW)  { src = Wv + (e - NX - 2*NW);  dst = Wqkv + (e - NX); }
      else                       { src = Wo + (e - NX - 3*NW);  dst = Wob  + (e - NX - 3*NW); }
      const float4 f = *(const float4*)src;
      uint2 o;
      o.x = cvtpk_bf16(f.x * sc, f.y * sc);
      o.y = cvtpk_bf16(f.z * sc, f.w * sc);
      *(uint2*)dst = o;
    } else {
      const int j = v - NV4;
      biasqkv[j] = (j < DIM) ? bq[j]
                 : (j < 2 * DIM) ? bk[j - DIM] * SCALE
                 : bv[j - 2 * DIM];
    }
  }
}

// ---------------------------------------------------------------------------
// NT GEMM: C[M,Nc] = A[M,K](bf16) @ B[Nc,K](bf16)^T + bias  (unchanged R6)
// ---------------------------------------------------------------------------
template <int MODE>
__global__ __launch_bounds__(256)
void gemm_nt(const unsigned short* __restrict__ A,
             const unsigned short* __restrict__ Bm,
             const float* __restrict__ bias,
             int M, int Nc, int K,
             unsigned short* __restrict__ Qb,
             unsigned short* __restrict__ Kb,
             unsigned short* __restrict__ Vt,
             float* __restrict__ Out) {
  __shared__ __align__(16) unsigned short As[128][64];  // linear, no pad
  __shared__ __align__(16) unsigned short Bs[128][64];

  const int t    = threadIdx.x;
  const int m0   = blockIdx.x * 128;
  const int n0   = blockIdx.y * 128;
  const int w    = t >> 6;
  const int lane = t & 63, quad = lane >> 4, ln = lane & 15;
  const int wm = (w >> 1) * 64, wn = (w & 1) * 64;

  const int srow = lane >> 3;       // 0..7 within an 8-row segment
  const int scol = (lane & 7) * 8;  // element col: 0,8,...,56

  floatx4 acc[4][4] = {};

  for (int k0 = 0; k0 < K; k0 += 64) {
    __syncthreads();
#pragma unroll
    for (int c = 0; c < 4; ++c) {
      const int seg = w * 4 + c;          // 0..15
      const int r   = seg * 8 + srow;
      gload16(&A [(size_t)(m0 + r) * K + k0 + scol], &As[0][0] + seg * 512);
      gload16(&Bm[(size_t)(n0 + r) * K + k0 + scol], &Bs[0][0] + seg * 512);
    }
    __syncthreads();

#pragma unroll
    for (int s = 0; s < 2; ++s) {
      short8 af[4], bf[4];
#pragma unroll
      for (int i = 0; i < 4; ++i)
        af[i] = *(const short8*)&As[wm + i * 16 + ln][s * 32 + quad * 8];
#pragma unroll
      for (int j = 0; j < 4; ++j)
        bf[j] = *(const short8*)&Bs[wn + j * 16 + ln][s * 32 + quad * 8];
#pragma unroll
      for (int i = 0; i < 4; ++i)
#pragma unroll
        for (int j = 0; j < 4; ++j)
          acc[i][j] = MFMA_BF16(af[i], bf[j], acc[i][j], 0, 0, 0);
    }
  }

  // epilogue; C layout: col = ln, row = quad*4 + r  [measured m89/m91]
#pragma unroll
  for (int i = 0; i < 4; ++i) {
#pragma unroll
    for (int j = 0; j < 4; ++j) {
      const int n = n0 + wn + j * 16 + ln;
      const float bn = bias[n];
#pragma unroll
      for (int r = 0; r < 4; ++r) {
        const int m = m0 + wm + i * 16 + quad * 4 + r;
        const float val = acc[i][j][r] + bn;
        if (MODE == 0) {
          const int b = m / SEQ, row = m - b * SEQ;
          const int which = n / DIM, rem = n - which * DIM;
          const int h = rem >> 6, d = rem & 63;
          const size_t bh = (size_t)(b * NH + h);
          if (which == 0)      Qb[(bh * SEQ + row) * 64 + d] = f2b(val);
          else if (which == 1) Kb[(bh * SEQ + row) * 64 + d] = f2b(val);
          else                 Vt[(bh * 64 + d) * SEQ + row] = f2b(val);
        } else {
          Out[(size_t)m * Nc + n] = val;
        }
      }
    }
  }
}

// ---------------------------------------------------------------------------
// Flash attention, max-free softmax, post-softmax decay mask.
// grid = (144 q-tiles of 16 rows, 12 heads); block = 256 = 4 waves = 4 batches.
// Per 32-key body (two-barrier, race-free):
//   barrier A: DMA for tile jt resident (vmcnt drained)
//   ds_read K frags (swz) + V frags (swz)
//   barrier B: lgkm drained on all waves => frag reads COMPLETE
//   DMA-stage K/V (own wave) + decay (waves 0,1, dbuf (jt+1)&1) for jt+1
//   QK^T (4 MFMA) | exp(S) -> P_lds | read P A-layout + decay from LDS |
//   pack bf16 (cvt_pk) | PV (4 MFMA)
// Swizzles (G21 pair: pre-swizzled global src, XOR'd ds_read; LDS linear):
//   K/D (128B rows): chunk ^= (row&7);  V (64B rows): chunk ^= ((row>>1)&3)
// ---------------------------------------------------------------------------
__global__ __launch_bounds__(256)
void attn_kernel(const unsigned short* __restrict__ Qb,
                 const unsigned short* __restrict__ Kb,
                 const unsigned short* __restrict__ Vt,
                 const float* __restrict__ decay,
                 unsigned short* __restrict__ attn_b) {
  __shared__ __align__(16) unsigned short Ks[4][32][64];  // 16KB, per-wave
  __shared__ __align__(16) unsigned short Vs[4][64][32];  // 16KB, per-wave
  __shared__ __align__(16) float Ds[2][16][32];           //  4KB, block-shared dbuf
  __shared__ __align__(16) float P_lds[4][16][36];        // 9.2KB, per-wave +4 pad

  const int t = threadIdx.x;
  const int w = t >> 6;                 // batch
  const int lane = t & 63, quad = lane >> 4, ln = lane & 15;
  const int qt = blockIdx.x;
  const int h  = blockIdx.y;
  const int q0 = qt * 16;

  const size_t bh = (size_t)(w * NH + h);
  const unsigned short* Qp = Qb + bh * SEQ * 64;
  const unsigned short* Kp = Kb + bh * SEQ * 64;
  const unsigned short* Vp = Vt + bh * 64 * SEQ;

  // ---- DMA lane constants (pre-swizzled sources; LDS dest linear) ----
  const int l8   = lane >> 3;                       // 0..7
  const int kcol = ((lane & 7) ^ l8) * 8;           // K src col chunk (elems)
  const int vrow = lane >> 2;                       // 0..15
  const int vcol = ((lane & 3) ^ (l8 & 3)) * 8;     // V src key chunk (elems)

  const unsigned short* ksrc  = Kp + (size_t)l8 * 64 + kcol;            // + j0*64 + c*512
  const unsigned short* vsrc0 = Vp + (size_t)(vrow +  0) * SEQ + vcol;  // + j0
  const unsigned short* vsrc1 = Vp + (size_t)(vrow + 16) * SEQ + vcol;
  const unsigned short* vsrc2 = Vp + (size_t)(vrow + 32) * SEQ + vcol;
  const unsigned short* vsrc3 = Vp + (size_t)(vrow + 48) * SEQ + vcol;
  const float* dsrc = decay + (size_t)h * SEQ * SEQ
                    + (size_t)(q0 + w * 8 + l8) * SEQ + ((lane & 7) ^ l8) * 4;  // + j0

  char* KsW = (char*)&Ks[w][0][0];
  char* VsW = (char*)&Vs[w][0][0];

  // stage tile starting at key j0 into the (single) K/V buffers and Ds[dbuf]
#define STAGE(J0, DBUF)                                                       \
  {                                                                           \
    const unsigned short* kp_ = ksrc + (size_t)(J0) * 64;                     \
    gload16(kp_,        KsW);                                                 \
    gload16(kp_ +  512, KsW + 1024);                                          \
    gload16(kp_ + 1024, KsW + 2048);                                          \
    gload16(kp_ + 1536, KsW + 3072);                                          \
    gload16(vsrc0 + (J0), VsW);                                               \
    gload16(vsrc1 + (J0), VsW + 1024);                                        \
    gload16(vsrc2 + (J0), VsW + 2048);                                        \
    gload16(vsrc3 + (J0), VsW + 3072);                                        \
    if (w < 2)                                                                \
      gload16(dsrc + (J0), (char*)&Ds[DBUF][0][0] + w * 1024);                \
  }

  STAGE(0, 0);  // prologue: tile 0, decay buf 0

  // Q fragments: A[m=ln][k=quad*8+j]
  short8 qf[2];
#pragma unroll
  for (int s = 0; s < 2; ++s)
    qf[s] = *(const short8*)&Qp[(size_t)(q0 + ln) * 64 + s * 32 + quad * 8];

  floatx4 O[4] = {};
  float den = 0.f;

  const int kx = (ln & 7) << 4;          // K/D read XOR (bytes)
  const int vx = ((ln >> 1) & 3) << 4;   // V read XOR (bytes)
  const char* KsR = (const char*)KsW;
  const char* VsR = (const char*)VsW;

  for (int jt = 0; jt < 72; ++jt) {
    __syncthreads();   // A: DMA for tile jt resident (K/V + Ds[jt&1])

    // K frags: row = tt*16+ln, d = s*32+quad*8  (swizzled read)
    short8 kf[2][2], vf[4];
#pragma unroll
    for (int s = 0; s < 2; ++s)
#pragma unroll
      for (int tt = 0; tt < 2; ++tt)
        kf[s][tt] = *(const short8*)(KsR + tt * 2048 + ln * 128
                                         + ((s * 64 + quad * 16) ^ kx));
    // V frags: row = dt*16+ln, keys = quad*8..  (swizzled read)
#pragma unroll
    for (int dt = 0; dt < 4; ++dt)
      vf[dt] = *(const short8*)(VsR + dt * 1024 + ln * 64 + ((quad * 16) ^ vx));

    __syncthreads();   // B: lgkm drained on all waves => frag reads COMPLETE

    // stage next tile: safe now, buffers free until barrier A of jt+1
    if (jt + 1 < 72) {
      STAGE((jt + 1) * 32, (jt + 1) & 1);
    }

    // S = Q @ K^T (K pre-scaled by 0.125 at pack time)
    floatx4 S[2] = {};
#pragma unroll
    for (int s = 0; s < 2; ++s)
#pragma unroll
      for (int tt = 0; tt < 2; ++tt)
        S[tt] = MFMA_BF16(qf[s], kf[s][tt], S[tt], 0, 0, 0);

    // exp(S) -> P_lds, C layout: row = quad*4+r, col = tt*16+ln
#pragma unroll
    for (int tt = 0; tt < 2; ++tt)
#pragma unroll
      for (int r = 0; r < 4; ++r)
        P_lds[w][quad * 4 + r][tt * 16 + ln] = __expf(S[tt][r]);

    // A-layout consume: row = ln, keys quad*8+{0..7}; decay from Ds[jt&1]
    const char* DsR = (const char*)&Ds[jt & 1][0][0];
    const float4 p0 = *(const float4*)&P_lds[w][ln][quad * 8];
    const float4 p1 = *(const float4*)&P_lds[w][ln][quad * 8 + 4];
    const float4 d0 = *(const float4*)(DsR + ln * 128 + ((quad * 32) ^ kx));
    const float4 d1 = *(const float4*)(DsR + ln * 128 + ((quad * 32 + 16) ^ kx));
    den += (p0.x + p0.y + p0.z + p0.w) + (p1.x + p1.y + p1.z + p1.w);
    union { short8 s8; unsigned u[4]; } pu;
    pu.u[0] = cvtpk_bf16(p0.x * d0.x, p0.y * d0.y);
    pu.u[1] = cvtpk_bf16(p0.z * d0.z, p0.w * d0.w);
    pu.u[2] = cvtpk_bf16(p1.x * d1.x, p1.y * d1.y);
    pu.u[3] = cvtpk_bf16(p1.z * d1.z, p1.w * d1.w);
#pragma unroll
    for (int dt = 0; dt < 4; ++dt)
      O[dt] = MFMA_BF16(pu.s8, vf[dt], O[dt], 0, 0, 0);
  }
#undef STAGE

  // den: sum the 4 quad partials for each row ln (lanes ln,16+ln,32+ln,48+ln)
  den += __shfl_xor(den, 16);
  den += __shfl_xor(den, 32);
  // O is C-layout (row = quad*4+r); den for row m lives in lanes with ln==m
  float dinv[4];
#pragma unroll
  for (int r = 0; r < 4; ++r)
    dinv[r] = 1.0f / __shfl(den, quad * 4 + r);

#pragma unroll
  for (int dt = 0; dt < 4; ++dt)
#pragma unroll
    for (int r = 0; r < 4; ++r)
      attn_b[((size_t)(w * SEQ + q0 + quad * 4 + r)) * DIM + h * 64 + dt * 16 + ln]
          = f2b(O[dt][r] * dinv[r]);
}

// ---------------------------------------------------------------------------
extern "C" void kernel_launch(void* const* d_in, const int* in_sizes, int n_in,
                              void* d_out, int out_size, void* d_ws, size_t ws_size,
                              hipStream_t stream) {
  const float* x     = (const float*)d_in[0];
  const float* decay = (const float*)d_in[1];
  const float* Wq    = (const float*)d_in[2];
  const float* bq    = (const float*)d_in[3];
  const float* Wk    = (const float*)d_in[4];
  const float* bk    = (const float*)d_in[5];
  const float* Wv    = (const float*)d_in[6];
  const float* bv    = (const float*)d_in[7];
  const float* Wo    = (const float*)d_in[8];
  const float* bo    = (const float*)d_in[9];
  float* out = (float*)d_out;

  char* ws = (char*)d_ws;
  size_t off = 0;
  auto alloc = [&](size_t bytes) {
    void* p = ws + off;
    off += (bytes + 255) & ~(size_t)255;
    return p;
  };
  unsigned short* xb      = (unsigned short*)alloc((size_t)MROW * DIM * 2);  // 14.2 MB
  unsigned short* Wqkv    = (unsigned short*)alloc((size_t)3 * NW * 2);      //  3.5 MB
  unsigned short* Wob     = (unsigned short*)alloc((size_t)NW * 2);          //  1.2 MB
  float*          biasqkv = (float*)alloc((size_t)3 * DIM * 4);
  unsigned short* Qb      = (unsigned short*)alloc((size_t)MROW * DIM * 2);  // 14.2 MB
  unsigned short* Kb      = (unsigned short*)alloc((size_t)MROW * DIM * 2);  // 14.2 MB
  unsigned short* Vt      = (unsigned short*)alloc((size_t)MROW * DIM * 2);  // 14.2 MB
  unsigned short* attn_b  = xb;  // xb is dead after gemm<0>; alias (~61 MB total)
  (void)ws_size; (void)in_sizes; (void)n_in; (void)out_size;

  pack_kernel<<<4096, 256, 0, stream>>>(x, Wq, bq, Wk, bk, Wv, bv, Wo,
                                        xb, Wqkv, Wob, biasqkv);

  gemm_nt<0><<<dim3(MROW / 128, 2304 / 128), 256, 0, stream>>>(
      xb, Wqkv, biasqkv, MROW, 3 * DIM, DIM, Qb, Kb, Vt, nullptr);

  attn_kernel<<<dim3(SEQ / 16, NH), 256, 0, stream>>>(Qb, Kb, Vt, decay, attn_b);

  gemm_nt<1><<<dim3(MROW / 128, DIM / 128), 256, 0, stream>>>(
      attn_b, Wob, bo, MROW, DIM, DIM, nullptr, nullptr, nullptr, out);
}